// Round 12
// baseline (202.550 us; speedup 1.0000x reference)
//
#include <hip/hip_runtime.h>
#include <math.h>

// Problem constants
#define N_SP   2304      // H*W = 48*48
#define CC     256       // C
#define GG     8         // groups
#define CGD    16        // channels per group
#define INTERC 128       // C/2
#define BB     2         // batch
#define NBLK_WC 288u     // wconv_bn grid size (barrier count)

#define LOG2E  1.4426950408889634f
#define CSHIFT 11.541560327111707f   // 8 * log2(e)

typedef _Float16 v4h __attribute__((ext_vector_type(4)));
typedef short    v4s __attribute__((ext_vector_type(4)));
typedef float    v4f __attribute__((ext_vector_type(4)));

__device__ inline unsigned f32_to_bf16_rne(float f) {
  unsigned u = __builtin_bit_cast(unsigned, f);
  return (u + 0x7FFFu + ((u >> 16) & 1u)) >> 16;
}

// ws layout (bytes).  XT/WH/WWB are in FRAGMENT-CONTIGUOUS layout:
//   half_idx(tile_row, ktile, quad, lane_l15, j) -> 512B-contiguous wave loads.
#define OFF_XT    0          // [sb=4][ntile144][ktile16][quad4][l15x4h] f16   4,718,592
#define OFF_WH    4718592    // [seg6][rowtile8][ktile16][quad4][l15x4h] f16     393,216
#define OFF_WWB   5111808    // [s2][otile16][ktile8][quad4][l15x4h] bf16        131,072
#define OFF_TH    5242880    // [sbg=32][n][16] f16                            2,359,296
#define OFF_PH    7602176    // [sbg=32][n][16] f16                            2,359,296
#define OFF_GT    9961472    // [sbg=32][16][m] bf16                           2,359,296
#define OFF_AT    12320768   // [sb=4][n][128] bf16                            2,359,296
#define OFF_STATS 14680064   // [s=2][2][256] f32                                  4,096
#define OFF_CTR   14684160   // barrier counter (unsigned)                            64

struct PackP { const float* src[8]; };   // 0..5: proj weights (s*3+proj), 6..7: W_w per s
struct BiasP { const float* b[6]; };     // s*3+proj

// ---------------------------------------------------------------------------
// K0: prep = pack weights into frag layout (blocks 0..1023) + transpose x
// into frag-layout XT (1024..1599) + zero stats & barrier counter (1600).
// theta weights (segs 0,3) pre-scaled by log2(e) -> exp2-domain scores.
// ---------------------------------------------------------------------------
__global__ __launch_bounds__(256) void prep_kernel(PackP p, _Float16* __restrict__ wh,
                                                   unsigned short* __restrict__ wwb,
                                                   const float* __restrict__ x0,
                                                   const float* __restrict__ x1,
                                                   _Float16* __restrict__ xt,
                                                   float* __restrict__ stats,
                                                   unsigned* __restrict__ ctr)
{
  int bid = blockIdx.x;
  if (bid == 1600) {
    ((float4*)stats)[threadIdx.x] = make_float4(0.f, 0.f, 0.f, 0.f);
    if (threadIdx.x == 0) *ctr = 0u;
    return;
  }
  if (bid < 1024) {
    int seg = bid >> 7;                              // 0..7
    int i = ((bid & 127) << 8) | threadIdx.x;        // 0..32767
    float v = p.src[seg][i];
    if (seg < 6) {
      if (seg == 0 || seg == 3) v *= LOG2E;          // theta
      int r = i >> 8, c = i & 255;                   // (128 rows, 256 c)
      int off = seg*32768 + (r>>4)*4096 + (c>>4)*256 + ((c>>2)&3)*64 + (r&15)*4 + (c&3);
      wh[off] = (_Float16)v;
    } else {
      int o = i >> 7, c = i & 127;                   // (256 o, 128 c)
      int off = (seg-6)*32768 + (o>>4)*2048 + (c>>4)*256 + ((c>>2)&3)*64 + (o&15)*4 + (c&3);
      wwb[off] = (unsigned short)f32_to_bf16_rne(v);
    }
    return;
  }
  // transpose path: x fp32 [c][n] -> XT frag layout f16
  __shared__ float ld[64][65];
  int b2 = bid - 1024;
  int ct = b2 & 3;
  int nt = (b2 >> 2) % 36;
  int sb = b2 / 144;
  const float* src = ((sb >> 1) ? x1 : x0) + (size_t)(sb & 1) * CC * N_SP;
  int t = threadIdx.x;
  int col = t & 63, rq = t >> 6;
  #pragma unroll
  for (int i = 0; i < 16; ++i) {
    int row = i * 4 + rq;
    ld[row][col] = src[(size_t)(ct * 64 + row) * N_SP + nt * 64 + col];
  }
  __syncthreads();
  int nl = t >> 2, ktl = t & 3;
  float v[16];
  #pragma unroll
  for (int j = 0; j < 16; ++j) v[j] = ld[ktl * 16 + j][nl];
  unsigned u[8];
  #pragma unroll
  for (int j = 0; j < 8; ++j)
    u[j] = __builtin_bit_cast(unsigned, __builtin_amdgcn_cvt_pkrtz(v[2*j], v[2*j+1]));
  int n_g = nt * 64 + nl;
  int ntile = n_g >> 4, n_l = n_g & 15;
  int ktile = ct * 4 + ktl;
  _Float16* base = xt + (size_t)sb * 589824 + ntile * 4096 + ktile * 256 + n_l * 4;
  #pragma unroll
  for (int q = 0; q < 4; ++q)
    *(uint2*)(base + q * 64) = make_uint2(u[2*q], u[2*q+1]);
}

// ---------------------------------------------------------------------------
// K1: proj via MFMA, all frag loads 512B-contiguous per wave.
// grid = 4(sb)*3(proj)*36(nt of 64) = 432 x 256; wave tile 32 rows x 64 n.
// ---------------------------------------------------------------------------
__global__ __launch_bounds__(256) void proj_mfma(BiasP bp, const _Float16* __restrict__ wh,
                                                 const _Float16* __restrict__ xt,
                                                 _Float16* __restrict__ theta, _Float16* __restrict__ phi,
                                                 unsigned short* __restrict__ gT)
{
  int bid = blockIdx.x;
  int nt   = bid % 36;
  int proj = (bid / 36) % 3;
  int sb   = bid / 108;
  int s    = sb >> 1;
  int tid = threadIdx.x, lane = tid & 63, wv = tid >> 6;
  int l15 = lane & 15, quad = lane >> 4;

  const _Float16* A = wh + (size_t)(s * 3 + proj) * 32768 + quad * 64 + l15 * 4;
  const _Float16* B = xt + (size_t)sb * 589824 + quad * 64 + l15 * 4;

  v4f acc[2][4];
  #pragma unroll
  for (int rt = 0; rt < 2; ++rt)
    #pragma unroll
    for (int c = 0; c < 4; ++c) acc[rt][c] = (v4f){0.f, 0.f, 0.f, 0.f};

  #pragma unroll 2
  for (int kt = 0; kt < 16; ++kt) {
    v4h a[2], b[4];
    #pragma unroll
    for (int rt = 0; rt < 2; ++rt)
      a[rt] = __builtin_bit_cast(v4h, *(const uint2*)(A + (wv*2 + rt) * 4096 + kt * 256));
    #pragma unroll
    for (int c = 0; c < 4; ++c)
      b[c] = __builtin_bit_cast(v4h, *(const uint2*)(B + (nt*4 + c) * 4096 + kt * 256));
    #pragma unroll
    for (int rt = 0; rt < 2; ++rt)
      #pragma unroll
      for (int c = 0; c < 4; ++c)
        acc[rt][c] = __builtin_amdgcn_mfma_f32_16x16x16f16(a[rt], b[c], acc[rt][c], 0, 0, 0);
  }

  const float* bias = bp.b[s * 3 + proj];
  float bscale = (proj == 0) ? LOG2E : 1.0f;
  #pragma unroll
  for (int rt = 0; rt < 2; ++rt) {
    int g   = wv * 2 + rt;            // row tile == group (rows = g*16+d)
    int sbg = sb * 8 + g;
    float bv[4];
    #pragma unroll
    for (int r = 0; r < 4; ++r) bv[r] = bias[g * 16 + quad * 4 + r] * bscale;
    if (proj < 2) {
      _Float16* outp = (proj == 0 ? theta : phi);
      #pragma unroll
      for (int c = 0; c < 4; ++c) {
        int n = nt * 64 + c * 16 + l15;
        unsigned u0 = __builtin_bit_cast(unsigned,
            __builtin_amdgcn_cvt_pkrtz(acc[rt][c][0] + bv[0], acc[rt][c][1] + bv[1]));
        unsigned u1 = __builtin_bit_cast(unsigned,
            __builtin_amdgcn_cvt_pkrtz(acc[rt][c][2] + bv[2], acc[rt][c][3] + bv[3]));
        *(uint2*)(outp + ((size_t)sbg * N_SP + n) * 16 + quad * 4) = make_uint2(u0, u1);
      }
    } else {
      #pragma unroll
      for (int c = 0; c < 4; ++c) {
        int n = nt * 64 + c * 16 + l15;
        #pragma unroll
        for (int r = 0; r < 4; ++r)
          gT[(size_t)sbg * 16 * N_SP + (size_t)(quad * 4 + r) * N_SP + n] =
              (unsigned short)f32_to_bf16_rne(acc[rt][c][r] + bv[r]);
      }
    }
  }
}

// ---------------------------------------------------------------------------
// K2: MFMA flash attention, exp2-domain, shift in MFMA C, lsum on matrix pipe.
// 576-thr blocks (9 waves, 144 rows), grid = 32 sbg * 16 nt = 512 blocks
// == exactly 2 blocks/CU (no tail). First 512 threads stage; all compute.
// sgt granule XOR-swizzle keeps SQ_LDS_BANK_CONFLICT at 0.
// ---------------------------------------------------------------------------
__global__ __launch_bounds__(576) void attn_kernel(const _Float16* __restrict__ theta,
                                                   const _Float16* __restrict__ phi,
                                                   const unsigned short* __restrict__ gT,
                                                   unsigned short* __restrict__ attoT)
{
  __shared__ short sphi[256 * 20];   // phi chunk [m_local][16], row stride 40 B
  __shared__ short sgt [16 * 260];   // gT chunk [d][granules swizzled], row stride 520 B

  int bid = blockIdx.x;
  int nt  = bid & 15;                // 16 tiles x 144 rows
  int sbg = bid >> 4;
  int g   = sbg & 7;
  int sb  = sbg >> 3;                // s*2+b

  int tid  = threadIdx.x;            // 0..575
  int lane = tid & 63;
  int wv   = tid >> 6;               // 0..8
  int l15  = lane & 15;
  int quad = lane >> 4;

  size_t base16 = (size_t)sbg * N_SP * CGD;

  // B-frag theta for this wave's 16 rows: B[k=quad*4+j][n=l15]
  int n_row = nt*144 + wv*16 + l15;
  v4h bTheta = __builtin_bit_cast(v4h,
      *(const uint2*)(theta + base16 + (size_t)n_row*16 + quad*4));

  const v4f Cinit = {-CSHIFT, -CSHIFT, -CSHIFT, -CSHIFT};
  const v4s vOnes = {0x3F80, 0x3F80, 0x3F80, 0x3F80};   // bf16 1.0 x4
  v4f acc  = {0.f, 0.f, 0.f, 0.f};
  v4f accL = {0.f, 0.f, 0.f, 0.f};

  // staging indices (first 512 threads only)
  int prow = tid >> 1, phalf = tid & 1;
  int gd = (tid & 255) >> 4, gseg = tid & 15, gk2 = ((tid >> 8) & 1) * 2, gs2 = gseg >> 2;

  for (int c0 = 0; c0 < N_SP; c0 += 256) {
    __syncthreads();
    if (tid < 512) {
      // phi: 256 rows x 32B; each thread stages 16B of one row
      uint4 v = *((const uint4*)(phi + base16 + (size_t)(c0 + prow)*16) + phalf);
      uint2* dst = (uint2*)((char*)sphi + prow*40 + phalf*16);
      dst[0] = make_uint2(v.x, v.y); dst[1] = make_uint2(v.z, v.w);
      // gT: 16 d x 512B; each thread stages 2 swizzled 8B granules
      uint4 gv = *(const uint4*)(gT + base16 + (size_t)gd*N_SP + c0 + gseg*16 + gk2*4);
      char* rowp = (char*)sgt + gd*520;
      *(uint2*)(rowp + (((gseg*4 + gk2 + 0) ^ gs2) * 8)) = make_uint2(gv.x, gv.y);
      *(uint2*)(rowp + (((gseg*4 + gk2 + 1) ^ gs2) * 8)) = make_uint2(gv.z, gv.w);
    }
    __syncthreads();

    #pragma unroll
    for (int sub = 0; sub < 16; ++sub) {
      int mb = sub * 16;
      // A-frag phi: A[m=l15][k=quad*4+j]
      v4h aPhi = __builtin_bit_cast(v4h,
          *(const uint2*)((const char*)sphi + (size_t)(mb + l15)*40 + quad*8));
      v4f S = __builtin_amdgcn_mfma_f32_16x16x16f16(aPhi, bTheta, Cinit, 0, 0, 0);
      // lane holds S[n=l15][m = c0+mb+quad*4+r], log2-domain incl. shift
      float e0 = __builtin_amdgcn_exp2f(S[0]);
      float e1 = __builtin_amdgcn_exp2f(S[1]);
      float e2 = __builtin_amdgcn_exp2f(S[2]);
      float e3 = __builtin_amdgcn_exp2f(S[3]);
      unsigned lo = __builtin_amdgcn_perm(__builtin_bit_cast(unsigned, e1),
                                          __builtin_bit_cast(unsigned, e0), 0x07060302u);
      unsigned hi = __builtin_amdgcn_perm(__builtin_bit_cast(unsigned, e3),
                                          __builtin_bit_cast(unsigned, e2), 0x07060302u);
      v4s P = __builtin_bit_cast(v4s, make_uint2(lo, hi));   // A[n=l15][k=quad*4+j]
      // B-frag g (bf16): B[k=quad*4+j][d=l15], swizzled granule read
      int kk = (sub >> 2) & 3;
      v4s gf = __builtin_bit_cast(v4s,
          *(const uint2*)((const char*)sgt + (size_t)l15*520 + sub*32 + ((quad ^ kk) * 8)));
      acc  = __builtin_amdgcn_mfma_f32_16x16x16bf16_1k(P, gf,    acc,  0, 0, 0);
      accL = __builtin_amdgcn_mfma_f32_16x16x16bf16_1k(P, vOnes, accL, 0, 0, 0);   // row sums
    }
  }

  // acc C-layout: row n_local = quad*4+r, col d = l15 -> AT[sb][n][g*16+d] bf16
  #pragma unroll
  for (int r2 = 0; r2 < 4; ++r2) {
    int n = nt*144 + wv*16 + quad*4 + r2;
    float inv = __builtin_amdgcn_rcpf(accL[r2]);
    attoT[((size_t)sb * N_SP + n) * INTERC + g*16 + l15] =
        (unsigned short)f32_to_bf16_rne(acc[r2] * inv);
  }
}

// ---------------------------------------------------------------------------
// K3: W 1x1 conv (MFMA) + BN stats (device atomics) + MANUAL GRID BARRIER +
// BN apply + residual + ReLU. Conv outputs never leave registers.
// Barrier: release-add on ws counter after threadfence; acquire-spin until
// NBLK_WC arrivals; stats re-read with agent-scope atomic loads (XCD-safe).
// 288 blocks x 256 thr << residency capacity -> all blocks dispatched, safe.
// ---------------------------------------------------------------------------
__global__ __launch_bounds__(256) void wconv_bn(const unsigned short* __restrict__ wwb,
                                                const unsigned short* __restrict__ attoT,
                                                const float* __restrict__ Wb0, const float* __restrict__ Wb1,
                                                float* __restrict__ stats, unsigned* __restrict__ ctr,
                                                const float* __restrict__ x0, const float* __restrict__ x1,
                                                const float* __restrict__ bg0, const float* __restrict__ bb0,
                                                const float* __restrict__ bg1, const float* __restrict__ bb1,
                                                float* __restrict__ out)
{
  int bid = blockIdx.x;
  int nt = bid % 36;
  int rh = (bid / 36) & 1;
  int sb = bid / 72;
  int s  = sb >> 1;
  int b  = sb & 1;
  int tid = threadIdx.x, lane = tid & 63, wv = tid >> 6;
  int l15 = lane & 15, quad = lane >> 4;

  const unsigned short* A = wwb + (size_t)s * 32768 + quad * 64 + l15 * 4;
  const unsigned short* B = attoT + (size_t)sb * N_SP * INTERC;

  v4f acc[2][4];
  #pragma unroll
  for (int rt = 0; rt < 2; ++rt)
    #pragma unroll
    for (int c = 0; c < 4; ++c) acc[rt][c] = (v4f){0.f, 0.f, 0.f, 0.f};

  #pragma unroll
  for (int kt = 0; kt < 8; ++kt) {
    v4s a[2], bfr[4];
    #pragma unroll
    for (int rt = 0; rt < 2; ++rt)
      a[rt] = __builtin_bit_cast(v4s, *(const uint2*)(A + (rh*8 + wv*2 + rt) * 2048 + kt * 256));
    #pragma unroll
    for (int c = 0; c < 4; ++c) {
      int n = nt * 64 + c * 16 + l15;
      bfr[c] = __builtin_bit_cast(v4s, *(const uint2*)(B + (size_t)n * 128 + kt * 16 + quad * 4));
    }
    #pragma unroll
    for (int rt = 0; rt < 2; ++rt)
      #pragma unroll
      for (int c = 0; c < 4; ++c)
        acc[rt][c] = __builtin_amdgcn_mfma_f32_16x16x16bf16_1k(a[rt], bfr[c], acc[rt][c], 0, 0, 0);
  }

  const float* Wb = s ? Wb1 : Wb0;
  float* sts = stats + (size_t)s * 512;
  float bv[2][4];
  #pragma unroll
  for (int rt = 0; rt < 2; ++rt) {
    int ob = rh * 128 + wv * 32 + rt * 16 + quad * 4;
    #pragma unroll
    for (int r = 0; r < 4; ++r) bv[rt][r] = Wb[ob + r];
    #pragma unroll
    for (int r = 0; r < 4; ++r) {
      float sp = 0.f, qp = 0.f;
      #pragma unroll
      for (int c = 0; c < 4; ++c) {
        float v = acc[rt][c][r] + bv[rt][r];
        sp += v; qp = fmaf(v, v, qp);
      }
      #pragma unroll
      for (int off = 1; off < 16; off <<= 1) {
        sp += __shfl_xor(sp, off, 64);
        qp += __shfl_xor(qp, off, 64);
      }
      if (l15 == 0) {
        atomicAdd(&sts[ob + r], sp);
        atomicAdd(&sts[256 + ob + r], qp);
      }
    }
  }

  // ---- manual grid barrier ----
  __threadfence();                       // make this block's atomics visible
  __syncthreads();                       // all waves done before arrival
  if (tid == 0) {
    __hip_atomic_fetch_add(ctr, 1u, __ATOMIC_RELEASE, __HIP_MEMORY_SCOPE_AGENT);
    while (__hip_atomic_load(ctr, __ATOMIC_ACQUIRE, __HIP_MEMORY_SCOPE_AGENT) < NBLK_WC)
      __builtin_amdgcn_s_sleep(8);
  }
  __syncthreads();

  // ---- BN apply + residual + ReLU from registers ----
  const float* bng = s ? bg1 : bg0;
  const float* bnb = s ? bb1 : bb0;
  const float* xin = (s ? x1 : x0) + (size_t)b * CC * N_SP;
  float* outp = out + (size_t)s * BB * CC * N_SP + (size_t)b * CC * N_SP;

  #pragma unroll
  for (int rt = 0; rt < 2; ++rt) {
    int ob = rh * 128 + wv * 32 + rt * 16 + quad * 4;
    #pragma unroll
    for (int r = 0; r < 4; ++r) {
      int o = ob + r;
      float S = __hip_atomic_load(&sts[o],       __ATOMIC_RELAXED, __HIP_MEMORY_SCOPE_AGENT);
      float Q = __hip_atomic_load(&sts[256 + o], __ATOMIC_RELAXED, __HIP_MEMORY_SCOPE_AGENT);
      float mean = S * (1.f / 4608.f);
      float var  = Q * (1.f / 4608.f) - mean * mean;
      float rstd = rsqrtf(var + 1e-5f);
      float scale = bng[o] * rstd;
      float shift = bnb[o] - mean * scale;
      #pragma unroll
      for (int c = 0; c < 4; ++c) {
        int n = nt * 64 + c * 16 + l15;
        float v = acc[rt][c][r] + bv[rt][r];
        float res = fmaf(v, scale, shift) + xin[(size_t)o * N_SP + n];
        outp[(size_t)o * N_SP + n] = fmaxf(res, 0.f);
      }
    }
  }
}

// ---------------------------------------------------------------------------
extern "C" void kernel_launch(void* const* d_in, const int* in_sizes, int n_in,
                              void* d_out, int out_size, void* d_ws, size_t ws_size,
                              hipStream_t stream)
{
  const float* xc = (const float*)d_in[0];
  const float* xr = (const float*)d_in[1];
  // per-sub input bases: cls=2, reg=12; order: g_w,g_b,theta_w,theta_b,phi_w,phi_b,W_w,W_b,bn_g,bn_b
  PackP pk;
  BiasP bp;
  for (int s = 0; s < 2; ++s) {
    int bs = 2 + s * 10;
    pk.src[s*3 + 0] = (const float*)d_in[bs + 2];  // theta_w
    pk.src[s*3 + 1] = (const float*)d_in[bs + 4];  // phi_w
    pk.src[s*3 + 2] = (const float*)d_in[bs + 0];  // g_w
    pk.src[6 + s]   = (const float*)d_in[bs + 6];  // W_w
    bp.b[s*3 + 0]   = (const float*)d_in[bs + 3];  // theta_b
    bp.b[s*3 + 1]   = (const float*)d_in[bs + 5];  // phi_b
    bp.b[s*3 + 2]   = (const float*)d_in[bs + 1];  // g_b
  }

  char* wsb = (char*)d_ws;
  _Float16*       XT    = (_Float16*)(wsb + OFF_XT);
  _Float16*       WH    = (_Float16*)(wsb + OFF_WH);
  unsigned short* WWB   = (unsigned short*)(wsb + OFF_WWB);
  _Float16*       THETA = (_Float16*)(wsb + OFF_TH);
  _Float16*       PHI   = (_Float16*)(wsb + OFF_PH);
  unsigned short* GT    = (unsigned short*)(wsb + OFF_GT);
  unsigned short* AT    = (unsigned short*)(wsb + OFF_AT);
  float*          STATS = (float*)(wsb + OFF_STATS);
  unsigned*       CTR   = (unsigned*)(wsb + OFF_CTR);

  prep_kernel<<<1601, 256, 0, stream>>>(pk, WH, WWB, xc, xr, XT, STATS, CTR);
  proj_mfma<<<432, 256, 0, stream>>>(bp, WH, XT, THETA, PHI, GT);
  attn_kernel<<<512, 576, 0, stream>>>(THETA, PHI, GT, AT);
  wconv_bn<<<288, 256, 0, stream>>>(WWB, AT,
                                    (const float*)d_in[9], (const float*)d_in[19],
                                    STATS, CTR, xc, xr,
                                    (const float*)d_in[10], (const float*)d_in[11],
                                    (const float*)d_in[20], (const float*)d_in[21],
                                    (float*)d_out);
}

// Round 13
// 163.092 us; speedup vs baseline: 1.2419x; 1.2419x over previous
//
#include <hip/hip_runtime.h>
#include <math.h>

// Problem constants
#define N_SP   2304      // H*W = 48*48
#define CC     256       // C
#define GG     8         // groups
#define CGD    16        // channels per group
#define INTERC 128       // C/2
#define BB     2         // batch

#define LOG2E  1.4426950408889634f
#define CSHIFT 11.541560327111707f   // 8 * log2(e)

typedef _Float16 v4h __attribute__((ext_vector_type(4)));
typedef short    v4s __attribute__((ext_vector_type(4)));
typedef float    v4f __attribute__((ext_vector_type(4)));

__device__ inline unsigned f32_to_bf16_rne(float f) {
  unsigned u = __builtin_bit_cast(unsigned, f);
  return (u + 0x7FFFu + ((u >> 16) & 1u)) >> 16;
}
__device__ inline float bf16_to_f32(unsigned h) {
  return __builtin_bit_cast(float, h << 16);
}

// ws layout (bytes).  XT/WH/WWB are in FRAGMENT-CONTIGUOUS layout:
//   half_idx(tile_row, ktile, quad, lane_l15, j) -> 512B-contiguous wave loads.
#define OFF_XT    0          // [sb=4][ntile144][ktile16][quad4][l15x4h] f16   4,718,592
#define OFF_WH    4718592    // [seg6][rowtile8][ktile16][quad4][l15x4h] f16     393,216
#define OFF_WWB   5111808    // [s2][otile16][ktile8][quad4][l15x4h] bf16        131,072
#define OFF_TH    5242880    // [sbg=32][n][16] f16                            2,359,296
#define OFF_PH    7602176    // [sbg=32][n][16] f16                            2,359,296
#define OFF_GT    9961472    // [sbg=32][16][m] bf16                           2,359,296
#define OFF_AT    12320768   // [sb=4][n][128] bf16                            2,359,296
#define OFF_WY    14680064   // [sb=4][o=256][n] bf16                          4,718,592
#define OFF_STATS 24117248   // [s=2][2][256] f32                                  4,096

struct PackP { const float* src[8]; };   // 0..5: proj weights (s*3+proj), 6..7: W_w per s
struct BiasP { const float* b[6]; };     // s*3+proj

// ---------------------------------------------------------------------------
// K0: prep = pack weights into frag layout (blocks 0..1023) + transpose x
// into frag-layout XT (1024..1599) + zero stats (block 1600).
// theta weights (segs 0,3) pre-scaled by log2(e) -> exp2-domain scores.
// ---------------------------------------------------------------------------
__global__ __launch_bounds__(256) void prep_kernel(PackP p, _Float16* __restrict__ wh,
                                                   unsigned short* __restrict__ wwb,
                                                   const float* __restrict__ x0,
                                                   const float* __restrict__ x1,
                                                   _Float16* __restrict__ xt,
                                                   float* __restrict__ stats)
{
  int bid = blockIdx.x;
  if (bid == 1600) {
    ((float4*)stats)[threadIdx.x] = make_float4(0.f, 0.f, 0.f, 0.f);
    return;
  }
  if (bid < 1024) {
    int seg = bid >> 7;                              // 0..7
    int i = ((bid & 127) << 8) | threadIdx.x;        // 0..32767
    float v = p.src[seg][i];
    if (seg < 6) {
      if (seg == 0 || seg == 3) v *= LOG2E;          // theta
      int r = i >> 8, c = i & 255;                   // (128 rows, 256 c)
      int off = seg*32768 + (r>>4)*4096 + (c>>4)*256 + ((c>>2)&3)*64 + (r&15)*4 + (c&3);
      wh[off] = (_Float16)v;
    } else {
      int o = i >> 7, c = i & 127;                   // (256 o, 128 c)
      int off = (seg-6)*32768 + (o>>4)*2048 + (c>>4)*256 + ((c>>2)&3)*64 + (o&15)*4 + (c&3);
      wwb[off] = (unsigned short)f32_to_bf16_rne(v);
    }
    return;
  }
  // transpose path: x fp32 [c][n] -> XT frag layout f16
  __shared__ float ld[64][65];
  int b2 = bid - 1024;
  int ct = b2 & 3;
  int nt = (b2 >> 2) % 36;
  int sb = b2 / 144;
  const float* src = ((sb >> 1) ? x1 : x0) + (size_t)(sb & 1) * CC * N_SP;
  int t = threadIdx.x;
  int col = t & 63, rq = t >> 6;
  #pragma unroll
  for (int i = 0; i < 16; ++i) {
    int row = i * 4 + rq;
    ld[row][col] = src[(size_t)(ct * 64 + row) * N_SP + nt * 64 + col];
  }
  __syncthreads();
  int nl = t >> 2, ktl = t & 3;
  float v[16];
  #pragma unroll
  for (int j = 0; j < 16; ++j) v[j] = ld[ktl * 16 + j][nl];
  unsigned u[8];
  #pragma unroll
  for (int j = 0; j < 8; ++j)
    u[j] = __builtin_bit_cast(unsigned, __builtin_amdgcn_cvt_pkrtz(v[2*j], v[2*j+1]));
  int n_g = nt * 64 + nl;
  int ntile = n_g >> 4, n_l = n_g & 15;
  int ktile = ct * 4 + ktl;
  _Float16* base = xt + (size_t)sb * 589824 + ntile * 4096 + ktile * 256 + n_l * 4;
  #pragma unroll
  for (int q = 0; q < 4; ++q)
    *(uint2*)(base + q * 64) = make_uint2(u[2*q], u[2*q+1]);
}

// ---------------------------------------------------------------------------
// K1: proj via MFMA, all frag loads 512B-contiguous per wave.
// grid = 4(sb)*3(proj)*36(nt of 64) = 432 x 256; wave tile 32 rows x 64 n.
// ---------------------------------------------------------------------------
__global__ __launch_bounds__(256) void proj_mfma(BiasP bp, const _Float16* __restrict__ wh,
                                                 const _Float16* __restrict__ xt,
                                                 _Float16* __restrict__ theta, _Float16* __restrict__ phi,
                                                 unsigned short* __restrict__ gT)
{
  int bid = blockIdx.x;
  int nt   = bid % 36;
  int proj = (bid / 36) % 3;
  int sb   = bid / 108;
  int s    = sb >> 1;
  int tid = threadIdx.x, lane = tid & 63, wv = tid >> 6;
  int l15 = lane & 15, quad = lane >> 4;

  const _Float16* A = wh + (size_t)(s * 3 + proj) * 32768 + quad * 64 + l15 * 4;
  const _Float16* B = xt + (size_t)sb * 589824 + quad * 64 + l15 * 4;

  v4f acc[2][4];
  #pragma unroll
  for (int rt = 0; rt < 2; ++rt)
    #pragma unroll
    for (int c = 0; c < 4; ++c) acc[rt][c] = (v4f){0.f, 0.f, 0.f, 0.f};

  #pragma unroll 2
  for (int kt = 0; kt < 16; ++kt) {
    v4h a[2], b[4];
    #pragma unroll
    for (int rt = 0; rt < 2; ++rt)
      a[rt] = __builtin_bit_cast(v4h, *(const uint2*)(A + (wv*2 + rt) * 4096 + kt * 256));
    #pragma unroll
    for (int c = 0; c < 4; ++c)
      b[c] = __builtin_bit_cast(v4h, *(const uint2*)(B + (nt*4 + c) * 4096 + kt * 256));
    #pragma unroll
    for (int rt = 0; rt < 2; ++rt)
      #pragma unroll
      for (int c = 0; c < 4; ++c)
        acc[rt][c] = __builtin_amdgcn_mfma_f32_16x16x16f16(a[rt], b[c], acc[rt][c], 0, 0, 0);
  }

  const float* bias = bp.b[s * 3 + proj];
  float bscale = (proj == 0) ? LOG2E : 1.0f;
  #pragma unroll
  for (int rt = 0; rt < 2; ++rt) {
    int g   = wv * 2 + rt;            // row tile == group (rows = g*16+d)
    int sbg = sb * 8 + g;
    float bv[4];
    #pragma unroll
    for (int r = 0; r < 4; ++r) bv[r] = bias[g * 16 + quad * 4 + r] * bscale;
    if (proj < 2) {
      _Float16* outp = (proj == 0 ? theta : phi);
      #pragma unroll
      for (int c = 0; c < 4; ++c) {
        int n = nt * 64 + c * 16 + l15;
        unsigned u0 = __builtin_bit_cast(unsigned,
            __builtin_amdgcn_cvt_pkrtz(acc[rt][c][0] + bv[0], acc[rt][c][1] + bv[1]));
        unsigned u1 = __builtin_bit_cast(unsigned,
            __builtin_amdgcn_cvt_pkrtz(acc[rt][c][2] + bv[2], acc[rt][c][3] + bv[3]));
        *(uint2*)(outp + ((size_t)sbg * N_SP + n) * 16 + quad * 4) = make_uint2(u0, u1);
      }
    } else {
      #pragma unroll
      for (int c = 0; c < 4; ++c) {
        int n = nt * 64 + c * 16 + l15;
        #pragma unroll
        for (int r = 0; r < 4; ++r)
          gT[(size_t)sbg * 16 * N_SP + (size_t)(quad * 4 + r) * N_SP + n] =
              (unsigned short)f32_to_bf16_rne(acc[rt][c][r] + bv[r]);
      }
    }
  }
}

// ---------------------------------------------------------------------------
// K2: MFMA flash attention, exp2-domain, shift in MFMA C, lsum on matrix pipe.
// DOUBLE-BUFFERED LDS (one barrier per chunk, 9 vs 18) + register prefetch
// of the next chunk's phi/gT (global latency hidden under compute).
// Hazard proof: thread storing buf at iter i passed barrier(i-1), which
// implies all threads finished compute(i-2) on buf. 37 KB LDS, 2 blocks/CU.
// 576-thr blocks (9 waves, 144 rows), grid = 32 sbg * 16 nt = 512 blocks.
// ---------------------------------------------------------------------------
__global__ __launch_bounds__(576) void attn_kernel(const _Float16* __restrict__ theta,
                                                   const _Float16* __restrict__ phi,
                                                   const unsigned short* __restrict__ gT,
                                                   unsigned short* __restrict__ attoT)
{
  __shared__ short sphi[2][256 * 20];   // phi chunk [m_local][16], row stride 40 B
  __shared__ short sgt [2][16 * 260];   // gT chunk [d][granules swizzled], row 520 B

  int bid = blockIdx.x;
  int nt  = bid & 15;                // 16 tiles x 144 rows
  int sbg = bid >> 4;
  int g   = sbg & 7;
  int sb  = sbg >> 3;                // s*2+b

  int tid  = threadIdx.x;            // 0..575
  int lane = tid & 63;
  int wv   = tid >> 6;               // 0..8
  int l15  = lane & 15;
  int quad = lane >> 4;

  size_t base16 = (size_t)sbg * N_SP * CGD;

  // B-frag theta for this wave's 16 rows: B[k=quad*4+j][n=l15]
  int n_row = nt*144 + wv*16 + l15;
  v4h bTheta = __builtin_bit_cast(v4h,
      *(const uint2*)(theta + base16 + (size_t)n_row*16 + quad*4));

  const v4f Cinit = {-CSHIFT, -CSHIFT, -CSHIFT, -CSHIFT};
  const v4s vOnes = {0x3F80, 0x3F80, 0x3F80, 0x3F80};   // bf16 1.0 x4
  v4f acc  = {0.f, 0.f, 0.f, 0.f};
  v4f accL = {0.f, 0.f, 0.f, 0.f};

  // staging indices (first 512 threads only)
  int prow = tid >> 1, phalf = tid & 1;
  int gd = (tid & 255) >> 4, gseg = tid & 15, gk2 = ((tid >> 8) & 1) * 2, gs2 = gseg >> 2;

  // prefetch chunk 0 into registers
  uint4 pv, gv;
  if (tid < 512) {
    pv = *((const uint4*)(phi + base16 + (size_t)prow*16) + phalf);
    gv = *(const uint4*)(gT + base16 + (size_t)gd*N_SP + gseg*16 + gk2*4);
  }

  for (int it = 0; it < 9; ++it) {
    int buf = it & 1;
    if (tid < 512) {
      // stage current chunk from registers into LDS buffer `buf`
      uint2* dst = (uint2*)((char*)sphi[buf] + prow*40 + phalf*16);
      dst[0] = make_uint2(pv.x, pv.y); dst[1] = make_uint2(pv.z, pv.w);
      char* rowp = (char*)sgt[buf] + gd*520;
      *(uint2*)(rowp + (((gseg*4 + gk2 + 0) ^ gs2) * 8)) = make_uint2(gv.x, gv.y);
      *(uint2*)(rowp + (((gseg*4 + gk2 + 1) ^ gs2) * 8)) = make_uint2(gv.z, gv.w);
      // issue next chunk's global loads (completion hidden under compute)
      if (it < 8) {
        int cn = (it + 1) * 256;
        pv = *((const uint4*)(phi + base16 + (size_t)(cn + prow)*16) + phalf);
        gv = *(const uint4*)(gT + base16 + (size_t)gd*N_SP + cn + gseg*16 + gk2*4);
      }
    }
    __syncthreads();

    const char* sphb = (const char*)sphi[buf];
    const char* sgtb = (const char*)sgt[buf];
    #pragma unroll
    for (int sub = 0; sub < 16; ++sub) {
      int mb = sub * 16;
      // A-frag phi: A[m=l15][k=quad*4+j]
      v4h aPhi = __builtin_bit_cast(v4h,
          *(const uint2*)(sphb + (size_t)(mb + l15)*40 + quad*8));
      v4f S = __builtin_amdgcn_mfma_f32_16x16x16f16(aPhi, bTheta, Cinit, 0, 0, 0);
      // lane holds S[n=l15][m = it*256+mb+quad*4+r], log2-domain incl. shift
      float e0 = __builtin_amdgcn_exp2f(S[0]);
      float e1 = __builtin_amdgcn_exp2f(S[1]);
      float e2 = __builtin_amdgcn_exp2f(S[2]);
      float e3 = __builtin_amdgcn_exp2f(S[3]);
      unsigned lo = __builtin_amdgcn_perm(__builtin_bit_cast(unsigned, e1),
                                          __builtin_bit_cast(unsigned, e0), 0x07060302u);
      unsigned hi = __builtin_amdgcn_perm(__builtin_bit_cast(unsigned, e3),
                                          __builtin_bit_cast(unsigned, e2), 0x07060302u);
      v4s P = __builtin_bit_cast(v4s, make_uint2(lo, hi));   // A[n=l15][k=quad*4+j]
      // B-frag g (bf16): B[k=quad*4+j][d=l15], swizzled granule read
      int kk = (sub >> 2) & 3;
      v4s gf = __builtin_bit_cast(v4s,
          *(const uint2*)(sgtb + (size_t)l15*520 + sub*32 + ((quad ^ kk) * 8)));
      acc  = __builtin_amdgcn_mfma_f32_16x16x16bf16_1k(P, gf,    acc,  0, 0, 0);
      accL = __builtin_amdgcn_mfma_f32_16x16x16bf16_1k(P, vOnes, accL, 0, 0, 0);   // row sums
    }
  }

  // acc C-layout: row n_local = quad*4+r, col d = l15 -> AT[sb][n][g*16+d] bf16
  #pragma unroll
  for (int r2 = 0; r2 < 4; ++r2) {
    int n = nt*144 + wv*16 + quad*4 + r2;
    float inv = __builtin_amdgcn_rcpf(accL[r2]);
    attoT[((size_t)sb * N_SP + n) * INTERC + g*16 + l15] =
        (unsigned short)f32_to_bf16_rne(acc[r2] * inv);
  }
}

// ---------------------------------------------------------------------------
// K3: W 1x1 conv via MFMA (frag-layout A) + fused BN stats + bf16 WY store.
// grid = 4(sb)*36(nt)*2(rh) = 288 x 256; wave tile 32 o x 64 n.
// ---------------------------------------------------------------------------
__global__ __launch_bounds__(256) void wconv_mfma(const unsigned short* __restrict__ wwb,
                                                  const unsigned short* __restrict__ attoT,
                                                  const float* __restrict__ Wb0, const float* __restrict__ Wb1,
                                                  unsigned short* __restrict__ wy, float* __restrict__ stats)
{
  int bid = blockIdx.x;
  int nt = bid % 36;
  int rh = (bid / 36) & 1;
  int sb = bid / 72;
  int s  = sb >> 1;
  int tid = threadIdx.x, lane = tid & 63, wv = tid >> 6;
  int l15 = lane & 15, quad = lane >> 4;

  const unsigned short* A = wwb + (size_t)s * 32768 + quad * 64 + l15 * 4;
  const unsigned short* B = attoT + (size_t)sb * N_SP * INTERC;

  v4f acc[2][4];
  #pragma unroll
  for (int rt = 0; rt < 2; ++rt)
    #pragma unroll
    for (int c = 0; c < 4; ++c) acc[rt][c] = (v4f){0.f, 0.f, 0.f, 0.f};

  #pragma unroll
  for (int kt = 0; kt < 8; ++kt) {
    v4s a[2], b[4];
    #pragma unroll
    for (int rt = 0; rt < 2; ++rt)
      a[rt] = __builtin_bit_cast(v4s, *(const uint2*)(A + (rh*8 + wv*2 + rt) * 2048 + kt * 256));
    #pragma unroll
    for (int c = 0; c < 4; ++c) {
      int n = nt * 64 + c * 16 + l15;
      b[c] = __builtin_bit_cast(v4s, *(const uint2*)(B + (size_t)n * 128 + kt * 16 + quad * 4));
    }
    #pragma unroll
    for (int rt = 0; rt < 2; ++rt)
      #pragma unroll
      for (int c = 0; c < 4; ++c)
        acc[rt][c] = __builtin_amdgcn_mfma_f32_16x16x16bf16_1k(a[rt], b[c], acc[rt][c], 0, 0, 0);
  }

  const float* Wb = s ? Wb1 : Wb0;
  float* sts = stats + (size_t)s * 512;
  #pragma unroll
  for (int rt = 0; rt < 2; ++rt) {
    float bv[4];
    int ob = rh * 128 + wv * 32 + rt * 16 + quad * 4;
    #pragma unroll
    for (int r = 0; r < 4; ++r) bv[r] = Wb[ob + r];
    #pragma unroll
    for (int r = 0; r < 4; ++r) {
      float sp = 0.f, qp = 0.f;
      #pragma unroll
      for (int c = 0; c < 4; ++c) {
        int n = nt * 64 + c * 16 + l15;
        float v = acc[rt][c][r] + bv[r];
        wy[((size_t)sb * CC + ob + r) * N_SP + n] = (unsigned short)f32_to_bf16_rne(v);
        sp += v; qp = fmaf(v, v, qp);
      }
      // reduce over the 16 lanes of this quad (same o)
      #pragma unroll
      for (int off = 1; off < 16; off <<= 1) {
        sp += __shfl_xor(sp, off, 64);
        qp += __shfl_xor(qp, off, 64);
      }
      if (l15 == 0) {
        atomicAdd(&sts[ob + r], sp);
        atomicAdd(&sts[256 + ob + r], qp);
      }
    }
  }
}

// ---------------------------------------------------------------------------
// K4: BN apply + residual + ReLU. WY read as bf16 (uint2 = 4 vals).
// grid = 2(sub)*256(o) = 512 x 256.
// ---------------------------------------------------------------------------
__global__ __launch_bounds__(256) void bn_apply(const unsigned short* __restrict__ wy,
                                                const float* __restrict__ x0, const float* __restrict__ x1,
                                                const float* __restrict__ g0, const float* __restrict__ b0,
                                                const float* __restrict__ g1, const float* __restrict__ b1,
                                                const float* __restrict__ stats,
                                                float* __restrict__ out)
{
  int o = blockIdx.x % 256;
  int s = blockIdx.x / 256;
  int t = threadIdx.x;
  const float* bng = s ? g1 : g0;
  const float* bnb = s ? b1 : b0;
  const float* xin = s ? x1 : x0;

  float S = stats[s * 512 + o];
  float Q = stats[s * 512 + 256 + o];
  float mean = S * (1.f / 4608.f);
  float var  = Q * (1.f / 4608.f) - mean * mean;
  float rstd = rsqrtf(var + 1e-5f);
  float scale = bng[o] * rstd;
  float shift = bnb[o] - mean * scale;

  #pragma unroll
  for (int b2 = 0; b2 < 2; ++b2) {
    const uint2*  wyp = (const uint2*)(wy + (size_t)((s*2 + b2)*CC + o) * N_SP);
    const float4* xp  = (const float4*)(xin + (size_t)(b2*CC + o) * N_SP);
    float4* op = (float4*)(out + (size_t)s * BB*CC*N_SP + (size_t)(b2*CC + o) * N_SP);
    for (int n = t; n < 576; n += 256) {
      uint2 w2 = wyp[n];
      float4 x4 = xp[n];
      float4 r;
      r.x = fmaxf(fmaf(bf16_to_f32(w2.x & 0xFFFFu), scale, shift) + x4.x, 0.f);
      r.y = fmaxf(fmaf(bf16_to_f32(w2.x >> 16),     scale, shift) + x4.y, 0.f);
      r.z = fmaxf(fmaf(bf16_to_f32(w2.y & 0xFFFFu), scale, shift) + x4.z, 0.f);
      r.w = fmaxf(fmaf(bf16_to_f32(w2.y >> 16),     scale, shift) + x4.w, 0.f);
      op[n] = r;
    }
  }
}

// ---------------------------------------------------------------------------
extern "C" void kernel_launch(void* const* d_in, const int* in_sizes, int n_in,
                              void* d_out, int out_size, void* d_ws, size_t ws_size,
                              hipStream_t stream)
{
  const float* xc = (const float*)d_in[0];
  const float* xr = (const float*)d_in[1];
  // per-sub input bases: cls=2, reg=12; order: g_w,g_b,theta_w,theta_b,phi_w,phi_b,W_w,W_b,bn_g,bn_b
  PackP pk;
  BiasP bp;
  for (int s = 0; s < 2; ++s) {
    int bs = 2 + s * 10;
    pk.src[s*3 + 0] = (const float*)d_in[bs + 2];  // theta_w
    pk.src[s*3 + 1] = (const float*)d_in[bs + 4];  // phi_w
    pk.src[s*3 + 2] = (const float*)d_in[bs + 0];  // g_w
    pk.src[6 + s]   = (const float*)d_in[bs + 6];  // W_w
    bp.b[s*3 + 0]   = (const float*)d_in[bs + 3];  // theta_b
    bp.b[s*3 + 1]   = (const float*)d_in[bs + 5];  // phi_b
    bp.b[s*3 + 2]   = (const float*)d_in[bs + 1];  // g_b
  }

  char* wsb = (char*)d_ws;
  _Float16*       XT    = (_Float16*)(wsb + OFF_XT);
  _Float16*       WH    = (_Float16*)(wsb + OFF_WH);
  unsigned short* WWB   = (unsigned short*)(wsb + OFF_WWB);
  _Float16*       THETA = (_Float16*)(wsb + OFF_TH);
  _Float16*       PHI   = (_Float16*)(wsb + OFF_PH);
  unsigned short* GT    = (unsigned short*)(wsb + OFF_GT);
  unsigned short* AT    = (unsigned short*)(wsb + OFF_AT);
  unsigned short* WY    = (unsigned short*)(wsb + OFF_WY);
  float*          STATS = (float*)(wsb + OFF_STATS);

  prep_kernel<<<1601, 256, 0, stream>>>(pk, WH, WWB, xc, xr, XT, STATS);
  proj_mfma<<<432, 256, 0, stream>>>(bp, WH, XT, THETA, PHI, GT);
  attn_kernel<<<512, 576, 0, stream>>>(THETA, PHI, GT, AT);
  wconv_mfma<<<288, 256, 0, stream>>>(WWB, AT,
                                      (const float*)d_in[9], (const float*)d_in[19], WY, STATS);
  bn_apply<<<512, 256, 0, stream>>>(WY, xc, xr,
                                    (const float*)d_in[10], (const float*)d_in[11],
                                    (const float*)d_in[20], (const float*)d_in[21],
                                    STATS, (float*)d_out);
}

// Round 14
// 161.277 us; speedup vs baseline: 1.2559x; 1.0113x over previous
//
#include <hip/hip_runtime.h>
#include <math.h>

// Problem constants
#define N_SP   2304      // H*W = 48*48
#define CC     256       // C
#define GG     8         // groups
#define CGD    16        // channels per group
#define INTERC 128       // C/2
#define BB     2         // batch

#define LOG2E  1.4426950408889634f
#define CSHIFT 11.541560327111707f   // 8 * log2(e)

typedef _Float16 v4h __attribute__((ext_vector_type(4)));
typedef short    v4s __attribute__((ext_vector_type(4)));
typedef float    v4f __attribute__((ext_vector_type(4)));

__device__ inline unsigned f32_to_bf16_rne(float f) {
  unsigned u = __builtin_bit_cast(unsigned, f);
  return (u + 0x7FFFu + ((u >> 16) & 1u)) >> 16;
}
__device__ inline float bf16_to_f32(unsigned h) {
  return __builtin_bit_cast(float, h << 16);
}

// ws layout (bytes).  WH/WWB in FRAGMENT-CONTIGUOUS layout (512B/wave-load).
#define OFF_WH    4718592    // [seg6][rowtile8][ktile16][quad4][l15x4h] f16     393,216
#define OFF_WWB   5111808    // [s2][otile16][ktile8][quad4][l15x4h] bf16        131,072
#define OFF_TH    5242880    // [sbg=32][n][16] f16                            2,359,296
#define OFF_PH    7602176    // [sbg=32][n][16] f16                            2,359,296
#define OFF_GT    9961472    // [sbg=32][16][m] bf16                           2,359,296
#define OFF_AT    12320768   // [sb=4][n][128] bf16                            2,359,296
#define OFF_WY    14680064   // [sb=4][o=256][n] bf16                          4,718,592
#define OFF_STATS 24117248   // [s=2][2][256] f32                                  4,096

struct PackP { const float* src[8]; };   // 0..5: proj weights (s*3+proj), 6..7: W_w per s
struct BiasP { const float* b[6]; };     // s*3+proj

// ---------------------------------------------------------------------------
// K0: prep = pack weights into frag layout (blocks 0..1023) + zero stats
// (block 1024). theta weights (segs 0,3) pre-scaled by log2(e).
// (x transpose now fused into proj_mfma -- XT stage eliminated.)
// ---------------------------------------------------------------------------
__global__ __launch_bounds__(256) void prep_kernel(PackP p, _Float16* __restrict__ wh,
                                                   unsigned short* __restrict__ wwb,
                                                   float* __restrict__ stats)
{
  int bid = blockIdx.x;
  if (bid == 1024) {
    ((float4*)stats)[threadIdx.x] = make_float4(0.f, 0.f, 0.f, 0.f);
    return;
  }
  int seg = bid >> 7;                              // 0..7
  int i = ((bid & 127) << 8) | threadIdx.x;        // 0..32767
  float v = p.src[seg][i];
  if (seg < 6) {
    if (seg == 0 || seg == 3) v *= LOG2E;          // theta
    int r = i >> 8, c = i & 255;                   // (128 rows, 256 c)
    int off = seg*32768 + (r>>4)*4096 + (c>>4)*256 + ((c>>2)&3)*64 + (r&15)*4 + (c&3);
    wh[off] = (_Float16)v;
  } else {
    int o = i >> 7, c = i & 127;                   // (256 o, 128 c)
    int off = (seg-6)*32768 + (o>>4)*2048 + (c>>4)*256 + ((c>>2)&3)*64 + (o&15)*4 + (c&3);
    wwb[off] = (unsigned short)f32_to_bf16_rne(v);
  }
}

// ---------------------------------------------------------------------------
// K1: proj via MFMA, self-staging x (transpose+f16 fused; no XT round-trip).
// Stage: thread t handles n = nt*64+(t&63), c-range (t>>6)*64..+63; x reads
// coalesced (256B/instr); LDS writes land frag-contiguous. A-frags from WH.
// grid = 4(sb)*3(proj)*36(nt of 64) = 432 x 256; wave tile 32 rows x 64 n.
// ---------------------------------------------------------------------------
__global__ __launch_bounds__(256) void proj_mfma(BiasP bp, const _Float16* __restrict__ wh,
                                                 const float* __restrict__ x0,
                                                 const float* __restrict__ x1,
                                                 _Float16* __restrict__ theta, _Float16* __restrict__ phi,
                                                 unsigned short* __restrict__ gT)
{
  __shared__ _Float16 bx[16384];   // 32 KB: [ntile4][ktile16][quad4][l15x4h]

  int bid = blockIdx.x;
  int nt   = bid % 36;
  int proj = (bid / 36) % 3;
  int sb   = bid / 108;
  int s    = sb >> 1;
  int b    = sb & 1;
  int tid = threadIdx.x, lane = tid & 63, wv = tid >> 6;
  int l15 = lane & 15, quad = lane >> 4;

  // ---- stage x tile [256 c][64 n] -> frag-layout f16 in LDS ----
  {
    const float* xp = (s ? x1 : x0) + (size_t)b * CC * N_SP + nt * 64 + (tid & 63);
    int cq = tid >> 6;                       // c block: cq*64 .. cq*64+63
    int ntile_l = (tid & 63) >> 4, n_l15 = tid & 15;
    _Float16* dst0 = bx + ntile_l * 4096 + n_l15 * 4;
    #pragma unroll
    for (int a = 0; a < 16; ++a) {
      int c0 = cq * 64 + a * 4;
      float f0 = xp[(size_t)(c0 + 0) * N_SP];
      float f1 = xp[(size_t)(c0 + 1) * N_SP];
      float f2 = xp[(size_t)(c0 + 2) * N_SP];
      float f3 = xp[(size_t)(c0 + 3) * N_SP];
      unsigned u0 = __builtin_bit_cast(unsigned, __builtin_amdgcn_cvt_pkrtz(f0, f1));
      unsigned u1 = __builtin_bit_cast(unsigned, __builtin_amdgcn_cvt_pkrtz(f2, f3));
      int kt = c0 >> 4, q = (c0 >> 2) & 3;
      *(uint2*)(dst0 + kt * 256 + q * 64) = make_uint2(u0, u1);
    }
  }
  __syncthreads();

  const _Float16* A = wh + (size_t)(s * 3 + proj) * 32768 + quad * 64 + l15 * 4;
  const _Float16* Bl = bx + quad * 64 + l15 * 4;

  v4f acc[2][4];
  #pragma unroll
  for (int rt = 0; rt < 2; ++rt)
    #pragma unroll
    for (int c = 0; c < 4; ++c) acc[rt][c] = (v4f){0.f, 0.f, 0.f, 0.f};

  #pragma unroll 4
  for (int kt = 0; kt < 16; ++kt) {
    v4h a[2], bf[4];
    #pragma unroll
    for (int rt = 0; rt < 2; ++rt)
      a[rt] = __builtin_bit_cast(v4h, *(const uint2*)(A + (wv*2 + rt) * 4096 + kt * 256));
    #pragma unroll
    for (int c = 0; c < 4; ++c)
      bf[c] = __builtin_bit_cast(v4h, *(const uint2*)(Bl + c * 4096 + kt * 256));
    #pragma unroll
    for (int rt = 0; rt < 2; ++rt)
      #pragma unroll
      for (int c = 0; c < 4; ++c)
        acc[rt][c] = __builtin_amdgcn_mfma_f32_16x16x16f16(a[rt], bf[c], acc[rt][c], 0, 0, 0);
  }

  const float* bias = bp.b[s * 3 + proj];
  float bscale = (proj == 0) ? LOG2E : 1.0f;
  #pragma unroll
  for (int rt = 0; rt < 2; ++rt) {
    int g   = wv * 2 + rt;            // row tile == group (rows = g*16+d)
    int sbg = sb * 8 + g;
    float bv[4];
    #pragma unroll
    for (int r = 0; r < 4; ++r) bv[r] = bias[g * 16 + quad * 4 + r] * bscale;
    if (proj < 2) {
      _Float16* outp = (proj == 0 ? theta : phi);
      #pragma unroll
      for (int c = 0; c < 4; ++c) {
        int n = nt * 64 + c * 16 + l15;
        unsigned u0 = __builtin_bit_cast(unsigned,
            __builtin_amdgcn_cvt_pkrtz(acc[rt][c][0] + bv[0], acc[rt][c][1] + bv[1]));
        unsigned u1 = __builtin_bit_cast(unsigned,
            __builtin_amdgcn_cvt_pkrtz(acc[rt][c][2] + bv[2], acc[rt][c][3] + bv[3]));
        *(uint2*)(outp + ((size_t)sbg * N_SP + n) * 16 + quad * 4) = make_uint2(u0, u1);
      }
    } else {
      #pragma unroll
      for (int c = 0; c < 4; ++c) {
        int n = nt * 64 + c * 16 + l15;
        #pragma unroll
        for (int r = 0; r < 4; ++r)
          gT[(size_t)sbg * 16 * N_SP + (size_t)(quad * 4 + r) * N_SP + n] =
              (unsigned short)f32_to_bf16_rne(acc[rt][c][r] + bv[r]);
      }
    }
  }
}

// ---------------------------------------------------------------------------
// K2: MFMA flash attention, exp2-domain, shift in MFMA C, lsum on matrix pipe.
// Double-buffered LDS (one barrier/chunk) + register prefetch of next chunk.
// 576-thr blocks (9 waves, 144 rows), grid = 32 sbg * 16 nt = 512 blocks
// == exactly 2 blocks/CU. sgt granule XOR-swizzle: 0 bank conflicts.
// ---------------------------------------------------------------------------
__global__ __launch_bounds__(576) void attn_kernel(const _Float16* __restrict__ theta,
                                                   const _Float16* __restrict__ phi,
                                                   const unsigned short* __restrict__ gT,
                                                   unsigned short* __restrict__ attoT)
{
  __shared__ short sphi[2][256 * 20];   // phi chunk [m_local][16], row stride 40 B
  __shared__ short sgt [2][16 * 260];   // gT chunk [d][granules swizzled], row 520 B

  int bid = blockIdx.x;
  int nt  = bid & 15;                // 16 tiles x 144 rows
  int sbg = bid >> 4;
  int g   = sbg & 7;
  int sb  = sbg >> 3;                // s*2+b

  int tid  = threadIdx.x;            // 0..575
  int lane = tid & 63;
  int wv   = tid >> 6;               // 0..8
  int l15  = lane & 15;
  int quad = lane >> 4;

  size_t base16 = (size_t)sbg * N_SP * CGD;

  // B-frag theta for this wave's 16 rows: B[k=quad*4+j][n=l15]
  int n_row = nt*144 + wv*16 + l15;
  v4h bTheta = __builtin_bit_cast(v4h,
      *(const uint2*)(theta + base16 + (size_t)n_row*16 + quad*4));

  const v4f Cinit = {-CSHIFT, -CSHIFT, -CSHIFT, -CSHIFT};
  const v4s vOnes = {0x3F80, 0x3F80, 0x3F80, 0x3F80};   // bf16 1.0 x4
  v4f acc  = {0.f, 0.f, 0.f, 0.f};
  v4f accL = {0.f, 0.f, 0.f, 0.f};

  // staging indices (first 512 threads only)
  int prow = tid >> 1, phalf = tid & 1;
  int gd = (tid & 255) >> 4, gseg = tid & 15, gk2 = ((tid >> 8) & 1) * 2, gs2 = gseg >> 2;

  // prefetch chunk 0 into registers
  uint4 pv, gv;
  if (tid < 512) {
    pv = *((const uint4*)(phi + base16 + (size_t)prow*16) + phalf);
    gv = *(const uint4*)(gT + base16 + (size_t)gd*N_SP + gseg*16 + gk2*4);
  }

  for (int it = 0; it < 9; ++it) {
    int buf = it & 1;
    if (tid < 512) {
      uint2* dst = (uint2*)((char*)sphi[buf] + prow*40 + phalf*16);
      dst[0] = make_uint2(pv.x, pv.y); dst[1] = make_uint2(pv.z, pv.w);
      char* rowp = (char*)sgt[buf] + gd*520;
      *(uint2*)(rowp + (((gseg*4 + gk2 + 0) ^ gs2) * 8)) = make_uint2(gv.x, gv.y);
      *(uint2*)(rowp + (((gseg*4 + gk2 + 1) ^ gs2) * 8)) = make_uint2(gv.z, gv.w);
      if (it < 8) {
        int cn = (it + 1) * 256;
        pv = *((const uint4*)(phi + base16 + (size_t)(cn + prow)*16) + phalf);
        gv = *(const uint4*)(gT + base16 + (size_t)gd*N_SP + cn + gseg*16 + gk2*4);
      }
    }
    __syncthreads();

    const char* sphb = (const char*)sphi[buf];
    const char* sgtb = (const char*)sgt[buf];
    #pragma unroll
    for (int sub = 0; sub < 16; ++sub) {
      int mb = sub * 16;
      v4h aPhi = __builtin_bit_cast(v4h,
          *(const uint2*)(sphb + (size_t)(mb + l15)*40 + quad*8));
      v4f S = __builtin_amdgcn_mfma_f32_16x16x16f16(aPhi, bTheta, Cinit, 0, 0, 0);
      float e0 = __builtin_amdgcn_exp2f(S[0]);
      float e1 = __builtin_amdgcn_exp2f(S[1]);
      float e2 = __builtin_amdgcn_exp2f(S[2]);
      float e3 = __builtin_amdgcn_exp2f(S[3]);
      unsigned lo = __builtin_amdgcn_perm(__builtin_bit_cast(unsigned, e1),
                                          __builtin_bit_cast(unsigned, e0), 0x07060302u);
      unsigned hi = __builtin_amdgcn_perm(__builtin_bit_cast(unsigned, e3),
                                          __builtin_bit_cast(unsigned, e2), 0x07060302u);
      v4s P = __builtin_bit_cast(v4s, make_uint2(lo, hi));   // A[n=l15][k=quad*4+j]
      int kk = (sub >> 2) & 3;
      v4s gf = __builtin_bit_cast(v4s,
          *(const uint2*)(sgtb + (size_t)l15*520 + sub*32 + ((quad ^ kk) * 8)));
      acc  = __builtin_amdgcn_mfma_f32_16x16x16bf16_1k(P, gf,    acc,  0, 0, 0);
      accL = __builtin_amdgcn_mfma_f32_16x16x16bf16_1k(P, vOnes, accL, 0, 0, 0);   // row sums
    }
  }

  #pragma unroll
  for (int r2 = 0; r2 < 4; ++r2) {
    int n = nt*144 + wv*16 + quad*4 + r2;
    float inv = __builtin_amdgcn_rcpf(accL[r2]);
    attoT[((size_t)sb * N_SP + n) * INTERC + g*16 + l15] =
        (unsigned short)f32_to_bf16_rne(acc[r2] * inv);
  }
}

// ---------------------------------------------------------------------------
// K3: W 1x1 conv via MFMA (frag-layout A) + fused BN stats + bf16 WY store.
// grid = 4(sb)*36(nt)*2(rh) = 288 x 256; wave tile 32 o x 64 n.
// ---------------------------------------------------------------------------
__global__ __launch_bounds__(256) void wconv_mfma(const unsigned short* __restrict__ wwb,
                                                  const unsigned short* __restrict__ attoT,
                                                  const float* __restrict__ Wb0, const float* __restrict__ Wb1,
                                                  unsigned short* __restrict__ wy, float* __restrict__ stats)
{
  int bid = blockIdx.x;
  int nt = bid % 36;
  int rh = (bid / 36) & 1;
  int sb = bid / 72;
  int s  = sb >> 1;
  int tid = threadIdx.x, lane = tid & 63, wv = tid >> 6;
  int l15 = lane & 15, quad = lane >> 4;

  const unsigned short* A = wwb + (size_t)s * 32768 + quad * 64 + l15 * 4;
  const unsigned short* B = attoT + (size_t)sb * N_SP * INTERC;

  v4f acc[2][4];
  #pragma unroll
  for (int rt = 0; rt < 2; ++rt)
    #pragma unroll
    for (int c = 0; c < 4; ++c) acc[rt][c] = (v4f){0.f, 0.f, 0.f, 0.f};

  #pragma unroll
  for (int kt = 0; kt < 8; ++kt) {
    v4s a[2], b[4];
    #pragma unroll
    for (int rt = 0; rt < 2; ++rt)
      a[rt] = __builtin_bit_cast(v4s, *(const uint2*)(A + (rh*8 + wv*2 + rt) * 2048 + kt * 256));
    #pragma unroll
    for (int c = 0; c < 4; ++c) {
      int n = nt * 64 + c * 16 + l15;
      b[c] = __builtin_bit_cast(v4s, *(const uint2*)(B + (size_t)n * 128 + kt * 16 + quad * 4));
    }
    #pragma unroll
    for (int rt = 0; rt < 2; ++rt)
      #pragma unroll
      for (int c = 0; c < 4; ++c)
        acc[rt][c] = __builtin_amdgcn_mfma_f32_16x16x16bf16_1k(a[rt], b[c], acc[rt][c], 0, 0, 0);
  }

  const float* Wb = s ? Wb1 : Wb0;
  float* sts = stats + (size_t)s * 512;
  #pragma unroll
  for (int rt = 0; rt < 2; ++rt) {
    float bv[4];
    int ob = rh * 128 + wv * 32 + rt * 16 + quad * 4;
    #pragma unroll
    for (int r = 0; r < 4; ++r) bv[r] = Wb[ob + r];
    #pragma unroll
    for (int r = 0; r < 4; ++r) {
      float sp = 0.f, qp = 0.f;
      #pragma unroll
      for (int c = 0; c < 4; ++c) {
        int n = nt * 64 + c * 16 + l15;
        float v = acc[rt][c][r] + bv[r];
        wy[((size_t)sb * CC + ob + r) * N_SP + n] = (unsigned short)f32_to_bf16_rne(v);
        sp += v; qp = fmaf(v, v, qp);
      }
      #pragma unroll
      for (int off = 1; off < 16; off <<= 1) {
        sp += __shfl_xor(sp, off, 64);
        qp += __shfl_xor(qp, off, 64);
      }
      if (l15 == 0) {
        atomicAdd(&sts[ob + r], sp);
        atomicAdd(&sts[256 + ob + r], qp);
      }
    }
  }
}

// ---------------------------------------------------------------------------
// K4: BN apply + residual + ReLU. WY read as bf16. 192 threads: 576 = 3x192
// exact (no divergent tail). grid = 2(sub)*256(o) = 512 x 192.
// ---------------------------------------------------------------------------
__global__ __launch_bounds__(192) void bn_apply(const unsigned short* __restrict__ wy,
                                                const float* __restrict__ x0, const float* __restrict__ x1,
                                                const float* __restrict__ g0, const float* __restrict__ b0,
                                                const float* __restrict__ g1, const float* __restrict__ b1,
                                                const float* __restrict__ stats,
                                                float* __restrict__ out)
{
  int o = blockIdx.x % 256;
  int s = blockIdx.x / 256;
  int t = threadIdx.x;
  const float* bng = s ? g1 : g0;
  const float* bnb = s ? b1 : b0;
  const float* xin = s ? x1 : x0;

  float S = stats[s * 512 + o];
  float Q = stats[s * 512 + 256 + o];
  float mean = S * (1.f / 4608.f);
  float var  = Q * (1.f / 4608.f) - mean * mean;
  float rstd = rsqrtf(var + 1e-5f);
  float scale = bng[o] * rstd;
  float shift = bnb[o] - mean * scale;

  #pragma unroll
  for (int b2 = 0; b2 < 2; ++b2) {
    const uint2*  wyp = (const uint2*)(wy + (size_t)((s*2 + b2)*CC + o) * N_SP);
    const float4* xp  = (const float4*)(xin + (size_t)(b2*CC + o) * N_SP);
    float4* op = (float4*)(out + (size_t)s * BB*CC*N_SP + (size_t)(b2*CC + o) * N_SP);
    #pragma unroll
    for (int k = 0; k < 3; ++k) {
      int n = t + k * 192;
      uint2 w2 = wyp[n];
      float4 x4 = xp[n];
      float4 r;
      r.x = fmaxf(fmaf(bf16_to_f32(w2.x & 0xFFFFu), scale, shift) + x4.x, 0.f);
      r.y = fmaxf(fmaf(bf16_to_f32(w2.x >> 16),     scale, shift) + x4.y, 0.f);
      r.z = fmaxf(fmaf(bf16_to_f32(w2.y & 0xFFFFu), scale, shift) + x4.z, 0.f);
      r.w = fmaxf(fmaf(bf16_to_f32(w2.y >> 16),     scale, shift) + x4.w, 0.f);
      op[n] = r;
    }
  }
}

// ---------------------------------------------------------------------------
extern "C" void kernel_launch(void* const* d_in, const int* in_sizes, int n_in,
                              void* d_out, int out_size, void* d_ws, size_t ws_size,
                              hipStream_t stream)
{
  const float* xc = (const float*)d_in[0];
  const float* xr = (const float*)d_in[1];
  // per-sub input bases: cls=2, reg=12; order: g_w,g_b,theta_w,theta_b,phi_w,phi_b,W_w,W_b,bn_g,bn_b
  PackP pk;
  BiasP bp;
  for (int s = 0; s < 2; ++s) {
    int bs = 2 + s * 10;
    pk.src[s*3 + 0] = (const float*)d_in[bs + 2];  // theta_w
    pk.src[s*3 + 1] = (const float*)d_in[bs + 4];  // phi_w
    pk.src[s*3 + 2] = (const float*)d_in[bs + 0];  // g_w
    pk.src[6 + s]   = (const float*)d_in[bs + 6];  // W_w
    bp.b[s*3 + 0]   = (const float*)d_in[bs + 3];  // theta_b
    bp.b[s*3 + 1]   = (const float*)d_in[bs + 5];  // phi_b
    bp.b[s*3 + 2]   = (const float*)d_in[bs + 1];  // g_b
  }

  char* wsb = (char*)d_ws;
  _Float16*       WH    = (_Float16*)(wsb + OFF_WH);
  unsigned short* WWB   = (unsigned short*)(wsb + OFF_WWB);
  _Float16*       THETA = (_Float16*)(wsb + OFF_TH);
  _Float16*       PHI   = (_Float16*)(wsb + OFF_PH);
  unsigned short* GT    = (unsigned short*)(wsb + OFF_GT);
  unsigned short* AT    = (unsigned short*)(wsb + OFF_AT);
  unsigned short* WY    = (unsigned short*)(wsb + OFF_WY);
  float*          STATS = (float*)(wsb + OFF_STATS);

  prep_kernel<<<1025, 256, 0, stream>>>(pk, WH, WWB, STATS);
  proj_mfma<<<432, 256, 0, stream>>>(bp, WH, xc, xr, THETA, PHI, GT);
  attn_kernel<<<512, 576, 0, stream>>>(THETA, PHI, GT, AT);
  wconv_mfma<<<288, 256, 0, stream>>>(WWB, AT,
                                      (const float*)d_in[9], (const float*)d_in[19], WY, STATS);
  bn_apply<<<512, 192, 0, stream>>>(WY, xc, xr,
                                    (const float*)d_in[10], (const float*)d_in[11],
                                    (const float*)d_in[20], (const float*)d_in[21],
                                    STATS, (float*)d_out);
}